// Round 9
// baseline (1322.614 us; speedup 1.0000x reference)
//
#include <hip/hip_runtime.h>
#include <hip/hip_bf16.h>

#define Vv 32000
#define Dm 768
#define Lm 4
#define Nst 16
#define Kc 4
#define Im 1536
#define DTr 48
#define Bt 4
#define Sq 2048
#define TOK (Bt*Sq)
#define EPSf 1e-5f
#define NC 64              // time chunks
#define CL 32              // chunk length = Sq/NC
#define QROWS (Bt*NC*16)   // 4096 rows of Q; Hin rows [QROWS, 2*QROWS)
#define LOG2E 1.4426950408889634f
#define LN2f  0.6931471805599453f

using bf16 = __hip_bfloat16;
typedef __bf16 bf16x8 __attribute__((ext_vector_type(8)));
typedef float f32x4 __attribute__((ext_vector_type(4)));
typedef float f32x2 __attribute__((ext_vector_type(2)));

__device__ __forceinline__ float b2f(bf16 x){ return __bfloat162float(x); }
__device__ __forceinline__ bf16 f2b(float x){ return __float2bfloat16(x); }
__device__ __forceinline__ float us2f(ushort u){ unsigned x = (unsigned)u << 16; return __builtin_bit_cast(float, x); }

// raw v_exp_f32: args always in (-60, 20] here, no denormal guard needed
__device__ __forceinline__ float ex2(float x){
#if __has_builtin(__builtin_amdgcn_exp2f)
  return __builtin_amdgcn_exp2f(x);
#else
  float r; asm("v_exp_f32 %0, %1" : "=v"(r) : "v"(x)); return r;
#endif
}
__device__ __forceinline__ float vlog2(float x){
#if __has_builtin(__builtin_amdgcn_logf)
  return __builtin_amdgcn_logf(x);
#else
  float r; asm("v_log_f32 %0, %1" : "=v"(r) : "v"(x)); return r;
#endif
}
__device__ __forceinline__ float frcp(float x){
#if __has_builtin(__builtin_amdgcn_rcpf)
  return __builtin_amdgcn_rcpf(x);
#else
  float r; asm("v_rcp_f32 %0, %1" : "=v"(r) : "v"(x)); return r;
#endif
}

#define GLDS(gp, lp) __builtin_amdgcn_global_load_lds( \
    (const __attribute__((address_space(1))) void*)(gp), \
    (__attribute__((address_space(3))) void*)(lp), 16, 0, 0)

// ---------------- f32 -> bf16 weight conversion (n multiple of 1024) --------
__global__ __launch_bounds__(256) void k_cvt(const float* __restrict__ src,
                                             bf16* __restrict__ dst, int n){
  int i = (blockIdx.x*256 + threadIdx.x)*4;
  if (i >= n) return;
  float4 v = *(const float4*)(src + i);
  bf16* o = dst + i;
  o[0]=f2b(v.x); o[1]=f2b(v.y); o[2]=f2b(v.z); o[3]=f2b(v.w);
}

// x_proj_w (L,80,Im) f32 -> (L,128,Im) bf16, rows 80..127 zero
__global__ __launch_bounds__(256) void k_cvt_xpw(const float* __restrict__ src,
                                                 bf16* __restrict__ dst){
  int idx = blockIdx.x*256 + threadIdx.x;
  int l = idx / (128*Im); int rem = idx - l*128*Im;
  int r = rem / Im;       int c = rem - r*Im;
  dst[idx] = (r < 80) ? f2b(src[((size_t)l*80 + r)*Im + c]) : f2b(0.f);
}

// dt_proj_w (L,Im,48) f32 -> (L,Im,64) bf16, cols 48..63 zero
__global__ __launch_bounds__(256) void k_cvt_dtw(const float* __restrict__ src,
                                                 bf16* __restrict__ dst){
  int idx = blockIdx.x*256 + threadIdx.x;
  int l = idx / (Im*64); int rem = idx - l*Im*64;
  int r = rem / 64;      int c = rem - r*64;
  dst[idx] = (c < 48) ? f2b(src[((size_t)l*Im + r)*48 + c]) : f2b(0.f);
}

// ---------------- embedding gather ------------------------------------------
__global__ __launch_bounds__(256) void k_embed(const int* __restrict__ ids,
                                               const float* __restrict__ emb,
                                               float* __restrict__ h){
  int t = blockIdx.x;
  const float4* e = (const float4*)(emb + (size_t)ids[t]*Dm);
  float4* o = (float4*)(h + (size_t)t*Dm);
  if (threadIdx.x < Dm/4) o[threadIdx.x] = e[threadIdx.x];
}

// ---------------- rmsnorm ---------------------------------------------------
__global__ __launch_bounds__(256) void k_rmsnorm(const float* __restrict__ h,
                                                 const float* __restrict__ w,
                                                 bf16* __restrict__ xb){
  int t = blockIdx.x;
  const float* x = h + (size_t)t*Dm;
  float v[3]; float ss = 0.f;
  #pragma unroll
  for (int j=0;j<3;j++){ v[j] = x[threadIdx.x + j*256]; ss += v[j]*v[j]; }
  #pragma unroll
  for (int off=32; off; off>>=1) ss += __shfl_xor(ss, off);
  __shared__ float sred[4];
  int wave = threadIdx.x>>6, lane = threadIdx.x&63;
  if (lane==0) sred[wave]=ss;
  __syncthreads();
  float tot = sred[0]+sred[1]+sred[2]+sred[3];
  float scale = rsqrtf(tot*(1.f/Dm) + EPSf);
  bf16* o = xb + (size_t)t*Dm;
  #pragma unroll
  for (int j=0;j<3;j++){ int d = threadIdx.x + j*256; o[d] = f2b(v[j]*scale*w[d]); }
}

__global__ __launch_bounds__(256) void k_rms_last(const float* __restrict__ h,
                                                  const float* __restrict__ w,
                                                  float* __restrict__ xf){
  int b = blockIdx.x;
  const float* x = h + ((size_t)b*Sq + (Sq-1))*Dm;
  float v[3]; float ss = 0.f;
  #pragma unroll
  for (int j=0;j<3;j++){ v[j] = x[threadIdx.x + j*256]; ss += v[j]*v[j]; }
  #pragma unroll
  for (int off=32; off; off>>=1) ss += __shfl_xor(ss, off);
  __shared__ float sred[4];
  int wave = threadIdx.x>>6, lane = threadIdx.x&63;
  if (lane==0) sred[wave]=ss;
  __syncthreads();
  float tot = sred[0]+sred[1]+sred[2]+sred[3];
  float scale = rsqrtf(tot*(1.f/Dm) + EPSf);
  float* o = xf + (size_t)b*Dm;
  #pragma unroll
  for (int j=0;j<3;j++){ int d = threadIdx.x + j*256; o[d] = v[j]*scale*w[d]; }
}

// ---------------- MFMA bf16 GEMM 128x128 (x_proj / dt) ----------------------
// MODE 0: bf16 out; MODE 1: f32 +=; MODE 3: softplus(x+bias) -> bf16
template<int MODE>
__global__ __launch_bounds__(256) void k_gemm(const bf16* __restrict__ A,
                                              const bf16* __restrict__ Bw,
                                              void* __restrict__ Cout,
                                              const float* __restrict__ bias,
                                              int M, int N, int K,
                                              int lda, int ldb, int ldc){
  __shared__ __align__(16) ushort Ash[128*32];
  __shared__ __align__(16) ushort Bsh[128*32];
  int tid = threadIdx.x;
  int bm = blockIdx.y, bn = blockIdx.x;
  int wave = tid >> 6, lane = tid & 63;
  int wrow = wave >> 1, wcol = wave & 1;
  int quad = lane >> 4, lq = lane & 15;

  f32x4 acc[4][4];
  #pragma unroll
  for (int a=0;a<4;a++)
    #pragma unroll
    for (int b=0;b<4;b++) acc[a][b] = (f32x4){0.f,0.f,0.f,0.f};

  const ushort* Ag = (const ushort*)A;
  const ushort* Bg = (const ushort*)Bw;

  for (int k0 = 0; k0 < K; k0 += 32) {
    __syncthreads();
    #pragma unroll
    for (int c = tid; c < 512; c += 256) {
      int row = c >> 2, col = (c & 3) * 8;
      GLDS(&Ag[(size_t)(bm*128 + row)*lda + k0 + col], &Ash[c*8]);
      GLDS(&Bg[(size_t)(bn*128 + row)*ldb + k0 + col], &Bsh[c*8]);
    }
    __syncthreads();
    bf16x8 af[4], bfr[4];
    #pragma unroll
    for (int a=0;a<4;a++){
      int m = wrow*64 + a*16 + lq;
      af[a] = __builtin_bit_cast(bf16x8, *(const uint4*)&Ash[m*32 + quad*8]);
    }
    #pragma unroll
    for (int b=0;b<4;b++){
      int n = wcol*64 + b*16 + lq;
      bfr[b] = __builtin_bit_cast(bf16x8, *(const uint4*)&Bsh[n*32 + quad*8]);
    }
    #pragma unroll
    for (int a=0;a<4;a++)
      #pragma unroll
      for (int b=0;b<4;b++)
        acc[a][b] = __builtin_amdgcn_mfma_f32_16x16x32_bf16(af[a], bfr[b], acc[a][b], 0, 0, 0);
  }
  #pragma unroll
  for (int a=0;a<4;a++)
    #pragma unroll
    for (int b=0;b<4;b++)
      #pragma unroll
      for (int r=0;r<4;r++){
        int row = bm*128 + wrow*64 + a*16 + quad*4 + r;
        int col = bn*128 + wcol*64 + b*16 + lq;
        size_t idx = (size_t)row*ldc + col;
        if (MODE == 0) ((bf16*)Cout)[idx] = f2b(acc[a][b][r]);
        else if (MODE == 1) ((float*)Cout)[idx] += acc[a][b][r];
        else {
          // softplus via raw v_exp/v_log, stored bf16 (dt)
          float v = acc[a][b][r] + bias[col];
          float sp;
          if (v > 20.f) sp = v;
          else { float e = ex2(v*LOG2E); sp = vlog2(1.f + e)*LN2f; }
          ((bf16*)Cout)[idx] = f2b(sp);
        }
      }
}

// ---------------- MFMA bf16 GEMM 256x256 8-phase (in_proj) -------------------
// BM=BN=256, BK=64, 512 threads = 8 waves (2M x 4N), per-wave 128x64 output.
// LDS 128KB: A[2][256][64] bf16 at 0, B[2][256][64] at 65536. Swizzle:
// storage_byte = (r<<7) + (colbyte ^ ((r&7)<<4)); GLDS dest linear, XOR
// pre-applied on the per-lane GLOBAL source (rule #21).
// Register-resident fragments -> 24 ds_read_b128/tile (minimum).
// vmcnt(4) at P1,P2,P4 covers each unit's deadline. Never vmcnt(0) mid-loop.
// Requires grid >= ~2x256 blocks (1 block/CU at 128KB LDS): in_proj only.
#define SA256(qm,k0s,bf_) { GLDS(Ag + sA[qm][0] + (k0s), lds + (bf_)*32768 + lA[qm][0]); \
                            GLDS(Ag + sA[qm][1] + (k0s), lds + (bf_)*32768 + lA[qm][1]); }
#define SB256(qn,k0s,bf_) { GLDS(Bg + sB[qn][0] + (k0s), lds + 65536 + (bf_)*32768 + lB[qn][0]); \
                            GLDS(Bg + sB[qn][1] + (k0s), lds + 65536 + (bf_)*32768 + lB[qn][1]); }
#define RD_A(qm_) do{ _Pragma("unroll") for(int m2=0;m2<4;m2++){ \
    int r = wm*128 + ((qm_)*4+m2)*16 + lq; \
    _Pragma("unroll") for(int kh=0;kh<2;kh++) \
      bA[m2][kh] = *(const uint4*)(Ab + (r<<7) + ((kh*64 + quad*16) ^ ((r&7)<<4))); } }while(0)
#define RD_B(qn_) do{ _Pragma("unroll") for(int n2=0;n2<2;n2++){ \
    int r = wn*64 + ((qn_)*2+n2)*16 + lq; \
    _Pragma("unroll") for(int kh=0;kh<2;kh++) \
      bB[qn_][n2][kh] = *(const uint4*)(Bb + (r<<7) + ((kh*64 + quad*16) ^ ((r&7)<<4))); } }while(0)
#define MMA256(qm_,qn_) do{ \
  __builtin_amdgcn_s_barrier(); \
  __builtin_amdgcn_sched_barrier(0); \
  __builtin_amdgcn_s_setprio(1); \
  _Pragma("unroll") for(int m2=0;m2<4;m2++) \
    _Pragma("unroll") for(int n2=0;n2<2;n2++) \
      _Pragma("unroll") for(int kh=0;kh<2;kh++) \
        acc[(qm_)*4+m2][(qn_)*2+n2] = __builtin_amdgcn_mfma_f32_16x16x32_bf16( \
          __builtin_bit_cast(bf16x8, bA[m2][kh]), __builtin_bit_cast(bf16x8, bB[qn_][n2][kh]), \
          acc[(qm_)*4+m2][(qn_)*2+n2], 0, 0, 0); \
  __builtin_amdgcn_s_setprio(0); \
  __builtin_amdgcn_s_barrier(); \
  __builtin_amdgcn_sched_barrier(0); \
}while(0)
#define VMW4 asm volatile("s_waitcnt vmcnt(4)":::"memory")

template<int MODE>
__global__ __launch_bounds__(512, 2) void k_gemm256(const bf16* __restrict__ A,
                                                    const bf16* __restrict__ Bw,
                                                    void* __restrict__ Cout,
                                                    int M, int N, int K,
                                                    int lda, int ldb, int ldc){
  __shared__ __align__(16) char lds[131072];
  int tid = threadIdx.x;
  int wave = tid >> 6, lane = tid & 63;
  int wm = wave >> 2, wn = wave & 3;
  int quad = lane >> 4, lq = lane & 15;
  // XCD-aware bijective swizzle (T1)
  int nx = gridDim.x;
  int nwg = nx * gridDim.y;
  int lin = blockIdx.y * nx + blockIdx.x;
  if ((nwg & 7) == 0){
    int cpx = nwg >> 3;
    lin = (lin & 7)*cpx + (lin >> 3);
  }
  int bm = lin / nx, bn = lin - bm*nx;
  const ushort* Ag = (const ushort*)A;
  const ushort* Bg = (const ushort*)Bw;

  size_t sA[2][2]; int lA[2][2];
  size_t sB[2][2]; int lB[2][2];
  #pragma unroll
  for (int qm=0; qm<2; qm++)
    #pragma unroll
    for (int d=0; d<2; d++){
      int r = d*128 + qm*64 + (tid>>3);
      int cb = ((tid&7)<<4) ^ ((r&7)<<4);
      sA[qm][d] = (size_t)(bm*256 + r)*lda + (cb>>1);
      lA[qm][d] = ((d*128 + qm*64)<<7) + tid*16;
    }
  #pragma unroll
  for (int qn=0; qn<2; qn++)
    #pragma unroll
    for (int d=0; d<2; d++){
      int g = 2*d + (wave>>2);
      int jj = tid & 255;
      int r = g*64 + qn*32 + (jj>>3);
      int cb = ((jj&7)<<4) ^ ((r&7)<<4);
      sB[qn][d] = (size_t)(bn*256 + r)*ldb + (cb>>1);
      lB[qn][d] = ((g*64 + qn*32)<<7) + jj*16;
    }

  f32x4 acc[8][4];
  #pragma unroll
  for (int a=0;a<8;a++)
    #pragma unroll
    for (int b=0;b<4;b++) acc[a][b] = (f32x4){0.f,0.f,0.f,0.f};

  SA256(0, 0, 0); SB256(0, 0, 0); SB256(1, 0, 0); SA256(1, 0, 0);
  VMW4;
  __builtin_amdgcn_s_barrier();
  __builtin_amdgcn_sched_barrier(0);

  uint4 bA[4][2], bB[2][2][2];
  int NT = K >> 6;
  for (int t = 0; t < NT-1; t++){
    int buf = t & 1, bufn = buf ^ 1;
    int k0n = (t+1) << 6;
    const char* Ab = lds + buf*32768;
    const char* Bb = lds + 65536 + buf*32768;
    RD_A(0); RD_B(0); SA256(0,k0n,bufn); VMW4; MMA256(0,0);
    RD_B(1);          SB256(0,k0n,bufn); VMW4; MMA256(0,1);
    RD_A(1);          SB256(1,k0n,bufn);       MMA256(1,0);
                      SA256(1,k0n,bufn); VMW4; MMA256(1,1);
  }
  {
    int buf = (NT-1) & 1;
    const char* Ab = lds + buf*32768;
    const char* Bb = lds + 65536 + buf*32768;
    RD_A(0); RD_B(0); asm volatile("s_waitcnt vmcnt(2)":::"memory"); MMA256(0,0);
    RD_B(1);          asm volatile("s_waitcnt vmcnt(0)":::"memory"); MMA256(0,1);
    RD_A(1);                                                          MMA256(1,0);
                                                                      MMA256(1,1);
  }

  #pragma unroll
  for (int mr=0; mr<8; mr++)
    #pragma unroll
    for (int nr=0; nr<4; nr++)
      #pragma unroll
      for (int rr=0; rr<4; rr++){
        int row = bm*256 + wm*128 + mr*16 + quad*4 + rr;
        int col = bn*256 + wn*64 + nr*16 + lq;
        size_t idx = (size_t)row*ldc + col;
        if (MODE == 0) ((bf16*)Cout)[idx] = f2b(acc[mr][nr][rr]);
        else ((float*)Cout)[idx] += acc[mr][nr][rr];
      }
}

// ------- MFMA bf16 GEMM 128x256 4-phase (out_proj, f32 +=) -------------------
// BM=128 x BN=256 -> 384 blocks (1.5 rounds of 256 CUs). 8 waves = 1M x 8N.
// LDS 96KB: A[2][128][64] at 0, B[2][256][64] at 32768. FIFO deadlines:
// vmcnt(5)@P2 covers P3's A1 reads; vmcnt(1)@P4 covers next tile's P1 reads.
#define SAn(qm_,k0s,bf_) GLDS(Ag + snA[qm_] + (k0s), lds + (bf_)*16384 + lnA[qm_])
#define SBn(k0s,bf_) { GLDS(Bg + snB[0] + (k0s), lds + 32768 + (bf_)*32768 + lnB[0]); \
                       GLDS(Bg + snB[1] + (k0s), lds + 32768 + (bf_)*32768 + lnB[1]); \
                       GLDS(Bg + snB[2] + (k0s), lds + 32768 + (bf_)*32768 + lnB[2]); \
                       GLDS(Bg + snB[3] + (k0s), lds + 32768 + (bf_)*32768 + lnB[3]); }
#define RDAn(h_) do{ _Pragma("unroll") for(int mf=0; mf<4; mf++){ \
    int r = ((h_)*4+mf)*16 + lq; \
    _Pragma("unroll") for(int kh=0;kh<2;kh++) \
      bA[mf][kh] = *(const uint4*)(Ab + (r<<7) + ((kh*64 + quad*16) ^ ((r&7)<<4))); } }while(0)
#define RDBn() do{ _Pragma("unroll") for(int n2=0;n2<2;n2++){ \
    int r = wn*32 + n2*16 + lq; \
    _Pragma("unroll") for(int kh=0;kh<2;kh++) \
      bB[n2][kh] = *(const uint4*)(Bb + (r<<7) + ((kh*64 + quad*16) ^ ((r&7)<<4))); } }while(0)
#define MMAn(h_,s_) do{ \
  __builtin_amdgcn_s_barrier(); \
  __builtin_amdgcn_sched_barrier(0); \
  __builtin_amdgcn_s_setprio(1); \
  _Pragma("unroll") for(int m2=0;m2<2;m2++) \
    _Pragma("unroll") for(int n2=0;n2<2;n2++) \
      _Pragma("unroll") for(int kh=0;kh<2;kh++) \
        acc[(h_)*4+(s_)*2+m2][n2] = __builtin_amdgcn_mfma_f32_16x16x32_bf16( \
          __builtin_bit_cast(bf16x8, bA[(s_)*2+m2][kh]), __builtin_bit_cast(bf16x8, bB[n2][kh]), \
          acc[(h_)*4+(s_)*2+m2][n2], 0, 0, 0); \
  __builtin_amdgcn_s_setprio(0); \
  __builtin_amdgcn_s_barrier(); \
  __builtin_amdgcn_sched_barrier(0); \
}while(0)

__global__ __launch_bounds__(512, 2) void k_gemm256n(const bf16* __restrict__ A,
                                                     const bf16* __restrict__ Bw,
                                                     float* __restrict__ Cout,
                                                     int M, int N, int K,
                                                     int lda, int ldb, int ldc){
  __shared__ __align__(16) char lds[98304];
  int tid = threadIdx.x;
  int wave = tid >> 6, lane = tid & 63;
  int wn = wave;                          // 8 waves across N
  int quad = lane >> 4, lq = lane & 15;
  // XCD-aware bijective swizzle (nwg = 384, %8 == 0)
  int nx = gridDim.x;
  int nwg = nx * gridDim.y;
  int lin = blockIdx.y * nx + blockIdx.x;
  if ((nwg & 7) == 0){
    int cpx = nwg >> 3;
    lin = (lin & 7)*cpx + (lin >> 3);
  }
  int bm = lin / nx, bn = lin - bm*nx;
  const ushort* Ag = (const ushort*)A;
  const ushort* Bg = (const ushort*)Bw;

  size_t snA[2]; int lnA[2];
  size_t snB[4]; int lnB[4];
  #pragma unroll
  for (int qm=0; qm<2; qm++){
    int r = qm*64 + (tid>>3);
    int cb = ((tid&7)<<4) ^ ((r&7)<<4);
    snA[qm] = (size_t)(bm*128 + r)*lda + (cb>>1);
    lnA[qm] = qm*8192 + tid*16;
  }
  #pragma unroll
  for (int d=0; d<4; d++){
    int r = d*64 + (tid>>3);
    int cb = ((tid&7)<<4) ^ ((r&7)<<4);
    snB[d] = (size_t)(bn*256 + r)*ldb + (cb>>1);
    lnB[d] = d*8192 + tid*16;
  }

  f32x4 acc[8][2];
  #pragma unroll
  for (int a=0;a<8;a++){ acc[a][0] = (f32x4){0.f,0.f,0.f,0.f}; acc[a][1] = (f32x4){0.f,0.f,0.f,0.f}; }

  // prologue: FIFO = B(4), A0(1), A1(1); wait through A0 (allow A1 outstanding)
  SBn(0, 0); SAn(0, 0, 0); SAn(1, 0, 0);
  asm volatile("s_waitcnt vmcnt(1)":::"memory");
  __builtin_amdgcn_s_barrier();
  __builtin_amdgcn_sched_barrier(0);

  uint4 bA[4][2], bB[2][2];
  int NT = K >> 6;
  for (int t = 0; t < NT-1; t++){
    int buf = t & 1, bufn = buf ^ 1;
    int k0n = (t+1) << 6;
    const char* Ab = lds + buf*16384;
    const char* Bb = lds + 32768 + buf*32768;
    RDAn(0); RDBn(); SBn(k0n,bufn); SAn(0,k0n,bufn);                        MMAn(0,0);
    asm volatile("s_waitcnt vmcnt(5)":::"memory");                          MMAn(0,1);
    RDAn(1); SAn(1,k0n,bufn);                                               MMAn(1,0);
    asm volatile("s_waitcnt vmcnt(1)":::"memory");                          MMAn(1,1);
  }
  { // tail tile
    int buf = (NT-1) & 1;
    const char* Ab = lds + buf*16384;
    const char* Bb = lds + 32768 + buf*32768;
    RDAn(0); RDBn();                                                        MMAn(0,0);
    asm volatile("s_waitcnt vmcnt(0)":::"memory");                          MMAn(0,1);
    RDAn(1);                                                                MMAn(1,0);
                                                                            MMAn(1,1);
  }

  #pragma unroll
  for (int mf=0; mf<8; mf++)
    #pragma unroll
    for (int n2=0; n2<2; n2++)
      #pragma unroll
      for (int rr=0; rr<4; rr++){
        int row = bm*128 + mf*16 + quad*4 + rr;
        int col = bn*256 + wn*32 + n2*16 + lq;
        Cout[(size_t)row*ldc + col] += acc[mf][n2][rr];
      }
}

// ------ depthwise causal conv K=4 + bias + SiLU, 8 channels/thread ----------
__global__ __launch_bounds__(192) void k_conv8(const bf16* __restrict__ proj,
                                               const float* __restrict__ cw,
                                               const float* __restrict__ cb,
                                               bf16* __restrict__ ut){
  int t = blockIdx.x;
  int i = threadIdx.x*8;                       // 192*8 = 1536 = Im
  int s = t & (Sq-1);
  float acc[8];
  {
    float4 b0 = *(const float4*)(cb + i);
    float4 b1 = *(const float4*)(cb + i + 4);
    acc[0]=b0.x; acc[1]=b0.y; acc[2]=b0.z; acc[3]=b0.w;
    acc[4]=b1.x; acc[5]=b1.y; acc[6]=b1.z; acc[7]=b1.w;
  }
  float4 w[8];
  #pragma unroll
  for (int j=0;j<8;j++) w[j] = *(const float4*)(cw + (size_t)(i+j)*4);
  const ushort* pr = (const ushort*)proj + (size_t)t*(2*Im) + i;
  if (s >= 3){
    #pragma unroll
    for (int k=0;k<Kc;k++){
      uint4 v = *(const uint4*)(pr + (ptrdiff_t)(k-3)*(2*Im));
      const ushort* u = (const ushort*)&v;
      #pragma unroll
      for (int j=0;j<8;j++) acc[j] += us2f(u[j]) * (&w[j].x)[k];
    }
  } else {
    #pragma unroll
    for (int k=0;k<Kc;k++){
      if (s + k - 3 >= 0){
        uint4 v = *(const uint4*)(pr + (ptrdiff_t)(k-3)*(2*Im));
        const ushort* u = (const ushort*)&v;
        #pragma unroll
        for (int j=0;j<8;j++) acc[j] += us2f(u[j]) * (&w[j].x)[k];
      }
    }
  }
  ushort o[8];
  #pragma unroll
  for (int j=0;j<8;j++){
    float sig = frcp(1.f + ex2(-acc[j]*LOG2E));
    o[j] = __builtin_bit_cast(ushort, f2b(acc[j]*sig));
  }
  *(uint4*)((ushort*)ut + (size_t)t*Im + i) = *(const uint4*)o;
}

// ============ chunked selective scan: thread per (b,i,chunk), 16 states/thread
// Q (rows [0,QROWS)) and Hin (rows [QROWS,2*QROWS)) live in dead u-columns of proj.
// R8: time-series inputs (dt/ut/gate) are cooperatively staged into LDS with
// bulk coalesced uint4 loads (rows of 512B) -- the scans were LATENCY-bound
// (1 small load per step, ~2 outstanding). LDS rows are 512B: lane reads 2B at
// tid*2 -> 2-way bank aliasing (free, m136). Compute unchanged (packed f32x2
// fast-decay path, runtime-guarded with scalar fallback).

// pass1: per-chunk local scan from h=0 -> Q (h_end, bf16), S (sum dt, f32)
__global__ __launch_bounds__(256) void k_scan1(const bf16* __restrict__ dt,
                                               const bf16* __restrict__ ut,
                                               const bf16* __restrict__ xdbl,
                                               const float* __restrict__ alog,
                                               bf16* __restrict__ Qb,   // proj base
                                               float* __restrict__ S){
  __shared__ float s_b[CL][16];                  // 2 KB: B per step
  __shared__ __align__(16) ushort s_dt[CL][256]; // 16 KB
  __shared__ __align__(16) ushort s_ut[CL][256]; // 16 KB
  int tid = threadIdx.x;
  int i = blockIdx.x*256 + tid;
  int b = blockIdx.y, c = blockIdx.z;
  size_t tok0 = (size_t)b*Sq + c*CL;
  // stage dt/ut tiles: CL rows x 512B, fully coalesced
  {
    const ushort* dsrc = (const ushort*)dt + tok0*Im + blockIdx.x*256;
    const ushort* usrc = (const ushort*)ut + tok0*Im + blockIdx.x*256;
    #pragma unroll
    for (int it = 0; it < (CL*32)/256; it++){
      int idx = it*256 + tid;
      int row = idx >> 5, c16 = (idx & 31)*8;
      *(uint4*)&s_dt[row][c16] = *(const uint4*)(dsrc + (size_t)row*Im + c16);
      *(uint4*)&s_ut[row][c16] = *(const uint4*)(usrc + (size_t)row*Im + c16);
    }
  }
  // stage B (cols 48..63 of xdbl) as f32
  {
    int row = tid >> 1, part = tid & 1;          // 128 slots >= CL*2
    if (row < CL){
      uint4 v = *(const uint4*)((const ushort*)xdbl + (tok0+row)*128 + 48 + part*8);
      const ushort* u = (const ushort*)&v;
      #pragma unroll
      for (int j=0;j<8;j++) s_b[row][part*8+j] = us2f(u[j]);
    }
  }
  float kn[16];
  {
    const float4* ap = (const float4*)(alog + (size_t)i*16);
    #pragma unroll
    for (int q=0;q<4;q++){
      float4 a4 = ap[q];
      kn[q*4+0] = -__expf(a4.x)*LOG2E; kn[q*4+1] = -__expf(a4.y)*LOG2E;
      kn[q*4+2] = -__expf(a4.z)*LOG2E; kn[q*4+3] = -__expf(a4.w)*LOG2E;
    }
  }
  bool fastp = true;
  #pragma unroll
  for (int n=1;n<16;n++)
    fastp = fastp && (fabsf(kn[n] - (float)(n+1)*kn[0]) <= 1e-4f*fabsf(kn[n]));
  __syncthreads();
  float sum = 0.f;
  int rq = (b*NC + c)*16;
  if (fastp){
    float k0 = kn[0];
    f32x2 h2[8];
    #pragma unroll
    for (int j=0;j<8;j++) h2[j] = (f32x2){0.f,0.f};
    for (int t = 0; t < CL; t++){
      float dtv = us2f(s_dt[t][tid]); float uv = us2f(s_ut[t][tid]);
      sum += dtv;
      float cdu = dtv*uv;
      f32x2 cdu2 = (f32x2){cdu, cdu};
      const f32x4* brow = (const f32x4*)&s_b[t][0];
      f32x4 B0=brow[0], B1=brow[1], B2=brow[2], B3=brow[3];
      f32x2 Bv2[8] = {
        __builtin_shufflevector(B0,B0,0,1), __builtin_shufflevector(B0,B0,2,3),
        __builtin_shufflevector(B1,B1,0,1), __builtin_shufflevector(B1,B1,2,3),
        __builtin_shufflevector(B2,B2,0,1), __builtin_shufflevector(B2,B2,2,3),
        __builtin_shufflevector(B3,B3,0,1), __builtin_shufflevector(B3,B3,2,3)};
      float p1 = ex2(k0*dtv);
      float p2 = p1*p1;
      f32x2 d2[8];
      d2[0] = (f32x2){p1,p2};
      f32x2 pp = (f32x2){p2,p2};
      d2[1] = d2[0]*pp;
      pp = (f32x2){d2[1][1], d2[1][1]};
      d2[2] = d2[0]*pp;
      d2[3] = d2[1]*pp;
      pp = (f32x2){d2[3][1], d2[3][1]};
      d2[4]=d2[0]*pp; d2[5]=d2[1]*pp; d2[6]=d2[2]*pp; d2[7]=d2[3]*pp;
      #pragma unroll
      for (int j=0;j<8;j++)
        h2[j] = d2[j]*h2[j] + cdu2*Bv2[j];
    }
    #pragma unroll
    for (int n=0;n<16;n++)
      Qb[(size_t)(rq+n)*2*Im + i] = f2b(h2[n>>1][n&1]);
  } else {
    float h[16];
    #pragma unroll
    for (int n=0;n<16;n++) h[n]=0.f;
    for (int t = 0; t < CL; t++){
      float dtv = us2f(s_dt[t][tid]); float uv = us2f(s_ut[t][tid]);
      sum += dtv;
      float cdu = dtv*uv;
      const f32x4* brow = (const f32x4*)&s_b[t][0];
      f32x4 B0=brow[0], B1=brow[1], B2=brow[2], B3=brow[3];
      float Bv[16] = {B0[0],B0[1],B0[2],B0[3],B1[0],B1[1],B1[2],B1[3],
                      B2[0],B2[1],B2[2],B2[3],B3[0],B3[1],B3[2],B3[3]};
      #pragma unroll
      for (int n=0;n<16;n++)
        h[n] = ex2(kn[n]*dtv)*h[n] + cdu*Bv[n];
    }
    #pragma unroll
    for (int n=0;n<16;n++)
      Qb[(size_t)(rq+n)*2*Im + i] = f2b(h[n]);
  }
  S[(size_t)(b*NC + c)*Im + i] = sum;
}

// pass2: stitch chunks: Hin[c] = h before chunk c
__global__ __launch_bounds__(256) void k_scan2(const bf16* __restrict__ Qb,
                                               const float* __restrict__ S,
                                               const float* __restrict__ alog,
                                               bf16* __restrict__ Hinb){
  int idx = blockIdx.x*256 + threadIdx.x;        // (b,n,i)
  int i = idx % Im; int bn = idx / Im;
  int n = bn & 15, b = bn >> 4;
  float kn = -__expf(alog[(size_t)i*16 + n])*LOG2E;
  float h = 0.f;
  for (int c = 0; c < NC; c++){
    size_t r = (size_t)((b*NC + c)*16 + n);
    Hinb[(QROWS + r)*2*Im + i] = f2b(h);
    float P = ex2(kn * S[(size_t)(b*NC + c)*Im + i]);
    h = P*h + b2f(Qb[r*2*Im + i]);
  }
}

// pass3: re-run chunk with h_in, produce y with fused epilogue
__global__ __launch_bounds__(256) void k_scan3(const bf16* __restrict__ dt,
                                               const bf16* __restrict__ ut,
                                               const bf16* __restrict__ xdbl,
                                               const bf16* __restrict__ proj,
                                               const float* __restrict__ alog,
                                               const float* __restrict__ dpar,
                                               const bf16* __restrict__ Hinb,
                                               bf16* __restrict__ y){
  __shared__ float s_bc[CL][32];                 // 4 KB: B|C per step
  __shared__ __align__(16) ushort s_dt[CL][256]; // 16 KB
  __shared__ __align__(16) ushort s_ut[CL][256]; // 16 KB
  __shared__ __align__(16) ushort s_gt[CL][256]; // 16 KB
  int tid = threadIdx.x;
  int i = blockIdx.x*256 + tid;
  int b = blockIdx.y, c = blockIdx.z;
  size_t tok0 = (size_t)b*Sq + c*CL;
  // stage dt/ut/gate tiles: CL rows x 512B, fully coalesced
  {
    const ushort* dsrc = (const ushort*)dt + tok0*Im + blockIdx.x*256;
    const ushort* usrc = (const ushort*)ut + tok0*Im + blockIdx.x*256;
    const ushort* gsrc = (const ushort*)proj + tok0*2*Im + Im + blockIdx.x*256;
    #pragma unroll
    for (int it = 0; it < (CL*32)/256; it++){
      int idx = it*256 + tid;
      int row = idx >> 5, c16 = (idx & 31)*8;
      *(uint4*)&s_dt[row][c16] = *(const uint4*)(dsrc + (size_t)row*Im + c16);
      *(uint4*)&s_ut[row][c16] = *(const uint4*)(usrc + (size_t)row*Im + c16);
      *(uint4*)&s_gt[row][c16] = *(const uint4*)(gsrc + (size_t)row*2*Im + c16);
    }
  }
  {
    int row = tid >> 1, part = tid & 1;
    if (row < CL){
      const ushort* src = (const ushort*)xdbl + (tok0+row)*128 + 48 + part*16;
      uint4 v0 = *(const uint4*)src;
      uint4 v1 = *(const uint4*)(src + 8);
      const ushort* u0 = (const ushort*)&v0;
      const ushort* u1 = (const ushort*)&v1;
      #pragma unroll
      for (int j=0;j<8;j++){
        s_bc[row][part*16 + j]     = us2f(u0[j]);
        s_bc[row][part*16 + 8 + j] = us2f(u1[j]);
      }
    }
  }
  float kn[16];
  {
    const float4* ap = (const float4*)(alog + (size_t)i*16);
    #pragma unroll
    for (int q=0;q<4;q++){
      float4 a4 = ap[q];
      kn[q*4+0] = -__expf(a4.x)*LOG2E; kn[q*4+1] = -__expf(a4.y)*LOG2E;
      kn[q*4+2] = -__expf(a4.z)*LOG2E; kn[q*4+3] = -__expf(a4.w)*LOG2E;
    }
  }
  bool fastp = true;
  #pragma unroll
  for (int n=1;n<16;n++)
    fastp = fastp && (fabsf(kn[n] - (float)(n+1)*kn[0]) <= 1e-4f*fabsf(kn[n]));
  float Dp = dpar[i];
  int rq = QROWS + (b*NC + c)*16;
  __syncthreads();
  if (fastp){
    float k0 = kn[0];
    f32x2 h2[8];
    #pragma unroll
    for (int j=0;j<8;j++)
      h2[j] = (f32x2){ b2f(Hinb[(size_t)(rq+2*j)*2*Im + i]),
                       b2f(Hinb[(size_t)(rq+2*j+1)*2*Im + i]) };
    for (int t = 0; t < CL; t++){
      float dtv = us2f(s_dt[t][tid]); float uv = us2f(s_ut[t][tid]);
      float g = us2f(s_gt[t][tid]);
      float cdu = dtv*uv;
      f32x2 cdu2 = (f32x2){cdu, cdu};
      const f32x4* brow = (const f32x4*)&s_bc[t][0];
      f32x4 B0=brow[0], B1=brow[1], B2=brow[2], B3=brow[3];
      f32x4 C0=brow[4], C1=brow[5], C2=brow[6], C3=brow[7];
      f32x2 Bv2[8] = {
        __builtin_shufflevector(B0,B0,0,1), __builtin_shufflevector(B0,B0,2,3),
        __builtin_shufflevector(B1,B1,0,1), __builtin_shufflevector(B1,B1,2,3),
        __builtin_shufflevector(B2,B2,0,1), __builtin_shufflevector(B2,B2,2,3),
        __builtin_shufflevector(B3,B3,0,1), __builtin_shufflevector(B3,B3,2,3)};
      f32x2 Cv2[8] = {
        __builtin_shufflevector(C0,C0,0,1), __builtin_shufflevector(C0,C0,2,3),
        __builtin_shufflevector(C1,C1,0,1), __builtin_shufflevector(C1,C1,2,3),
        __builtin_shufflevector(C2,C2,0,1), __builtin_shufflevector(C2,C2,2,3),
        __builtin_shufflevector(C3,C3,0,1), __builtin_shufflevector(C3,C3,2,3)};
      float p1 = ex2(k0*dtv);
      float p2 = p1*p1;
      f32x2 d2[8];
      d2[0] = (f32x2){p1,p2};
      f32x2 pp = (f32x2){p2,p2};
      d2[1] = d2[0]*pp;
      pp = (f32x2){d2[1][1], d2[1][1]};
      d2[2] = d2[0]*pp;
      d2[3] = d2[1]*pp;
      pp = (f32x2){d2[3][1], d2[3][1]};
      d2[4]=d2[0]*pp; d2[5]=d2[1]*pp; d2[6]=d2[2]*pp; d2[7]=d2[3]*pp;
      f32x2 yv2 = (f32x2){0.f, 0.f};
      #pragma unroll
      for (int j=0;j<8;j++){
        h2[j] = d2[j]*h2[j] + cdu2*Bv2[j];
        yv2 = yv2 + h2[j]*Cv2[j];
      }
      float yv = yv2[0] + yv2[1];
      float sig = frcp(1.f + ex2(-g*LOG2E));
      float outv = (yv + uv*Dp) * (g*sig);
      y[(tok0+t)*Im + i] = f2b(outv);
    }
  } else {
    float h[16];
    #pragma unroll
    for (int n=0;n<16;n++)
      h[n] = b2f(Hinb[(size_t)(rq+n)*2*Im + i]);
    for (int t = 0; t < CL; t++){
      float dtv = us2f(s_dt[t][tid]); float uv = us2f(s_ut[t][tid]);
      float g = us2f(s_gt[t][tid]);
      float cdu = dtv*uv;
      const f32x4* brow = (const f32x4*)&s_bc[t][0];
      f32x4 B0=brow[0], B1=brow[1], B2=brow[2], B3=brow[3];
      f32x4 C0=brow[4], C1=brow[5], C2=brow[6], C3=brow[7];
      float Bv[16] = {B0[0],B0[1],B0[2],B0[3],B1[0],B1[1],B1[2],B1[3],
                      B2[0],B2[1],B2[2],B2[3],B3[0],B3[1],B3[2],B3[3]};
      float Cv[16] = {C0[0],C0[1],C0[2],C0[3],C1[0],C1[1],C1[2],C1[3],
                      C2[0],C2[1],C2[2],C2[3],C3[0],C3[1],C3[2],C3[3]};
      float yv = 0.f;
      #pragma unroll
      for (int n=0;n<16;n++){
        h[n] = ex2(kn[n]*dtv)*h[n] + cdu*Bv[n];
        yv += h[n]*Cv[n];
      }
      float sig = frcp(1.f + ex2(-g*LOG2E));
      float outv = (yv + uv*Dp) * (g*sig);
      y[(tok0+t)*Im + i] = f2b(outv);
    }
  }
}

// ---------------- logits (f32 out) ------------------------------------------
__global__ __launch_bounds__(256) void k_logits(const float* __restrict__ xf,
                                                const float* __restrict__ emb,
                                                float* __restrict__ out){
  __shared__ __align__(16) float xs[Bt*Dm];
  for (int j = threadIdx.x; j < Bt*Dm; j += 256) xs[j] = xf[j];
  __syncthreads();
  int wave = threadIdx.x>>6, lane = threadIdx.x&63;
  int v = blockIdx.x*4 + wave;
  const float4* e4 = (const float4*)(emb + (size_t)v*Dm);
  float a0=0.f,a1=0.f,a2=0.f,a3=0.f;
  for (int j = lane; j < Dm/4; j += 64){
    float4 ev = e4[j];
    float4 x0 = *(const float4*)&xs[j*4];
    float4 x1 = *(const float4*)&xs[Dm + j*4];
    float4 x2 = *(const float4*)&xs[2*Dm + j*4];
    float4 x3 = *(const float4*)&xs[3*Dm + j*4];
    a0 += ev.x*x0.x + ev.y*x0.y + ev.z*x0.z + ev.w*x0.w;
    a1 += ev.x*x1.x + ev.y*x1.y + ev.z*x1.z + ev.w*x1.w;
    a2 += ev.x*x2.x + ev.y*x2.y + ev.z*x2.z + ev.w*x2.w;
    a3 += ev.x*x3.x + ev.y*x3.y + ev.z*x3.z + ev.w*x3.w;
  }
  #pragma unroll
  for (int off=32; off; off>>=1){
    a0+=__shfl_xor(a0,off); a1+=__shfl_xor(a1,off);
    a2+=__shfl_xor(a2,off); a3+=__shfl_xor(a3,off);
  }
  if (lane==0){
    out[v]        = a0;
    out[Vv+v]     = a1;
    out[2*Vv+v]   = a2;
    out[3*Vv+v]   = a3;
  }
}

extern "C" void kernel_launch(void* const* d_in, const int* in_sizes, int n_in,
                              void* d_out, int out_size, void* d_ws, size_t ws_size,
                              hipStream_t stream){
  const int*   ids   = (const int*)d_in[0];
  const float* emb   = (const float*)d_in[1];
  const float* normw = (const float*)d_in[2];
  const float* inw   = (const float*)d_in[3];
  const float* cw    = (const float*)d_in[4];
  const float* cb    = (const float*)d_in[5];
  const float* xpw   = (const float*)d_in[6];
  const float* dtw   = (const float*)d_in[7];
  const float* dtb   = (const float*)d_in[8];
  const float* alog  = (const float*)d_in[9];
  const float* dpar  = (const float*)d_in[10];
  const float* outw  = (const float*)d_in[11];
  const float* normf = (const float*)d_in[12];
  float* out = (float*)d_out;

  char* p = (char*)d_ws;
  float* h    = (float*)p;  p += (size_t)TOK*Dm*4;        // 25.2 MB
  bf16*  xb   = (bf16*)p;   p += (size_t)TOK*Dm*2;        // 12.6 MB (S aliases tail)
  bf16*  proj = (bf16*)p;   p += (size_t)TOK*2*Im*2;      // 50.3 MB (u|gate; Q/Hin in u cols)
  bf16*  utb  = (bf16*)p;   p += (size_t)TOK*Im*2;        // 25.2 MB
  bf16*  xdbl = (bf16*)p;   p += (size_t)TOK*128*2;       // 2.1 MB
  bf16*  dtq  = (bf16*)p;   p += (size_t)TOK*Im*2;        // 25.2 MB (dt, bf16)
  bf16*  yb   = (bf16*)p;   p += (size_t)TOK*Im*2;        // 25.2 MB
  float* xf   = (float*)p;  p += (size_t)Bt*Dm*4;
  bf16*  inwb = (bf16*)p;   p += (size_t)Lm*2*Im*Dm*2;
  bf16*  outwb= (bf16*)p;   p += (size_t)Lm*Dm*Im*2;
  bf16*  xpwb = (bf16*)p;   p += (size_t)Lm*128*Im*2;
  bf16*  dtwb = (bf16*)p;   p += (size_t)Lm*Im*64*2;      // < proven 222 MB total
  // scan scratch: S (f32, 1.57 MB) aliases xb (dead during scan)
  float* S = (float*)xb;

  { int n = Lm*2*Im*Dm; k_cvt<<<n/1024, 256, 0, stream>>>(inw, inwb, n); }
  { int n = Lm*Dm*Im;   k_cvt<<<n/1024, 256, 0, stream>>>(outw, outwb, n); }
  k_cvt_xpw<<<(Lm*128*Im)/256, 256, 0, stream>>>(xpw, xpwb);
  k_cvt_dtw<<<(Lm*Im*64)/256, 256, 0, stream>>>(dtw, dtwb);

  k_embed<<<TOK, 256, 0, stream>>>(ids, emb, h);

  for (int l = 0; l < Lm; l++){
    k_rmsnorm<<<TOK, 256, 0, stream>>>(h, normw + l*Dm, xb);
    k_gemm256<0><<<dim3((2*Im)/256, TOK/256), 512, 0, stream>>>(
        xb, inwb + (size_t)l*2*Im*Dm, proj, TOK, 2*Im, Dm, Dm, Dm, 2*Im);
    k_conv8<<<TOK, 192, 0, stream>>>(
        proj, cw + (size_t)l*Im*Kc, cb + (size_t)l*Im, utb);
    k_gemm<0><<<dim3(1, TOK/128), 256, 0, stream>>>(
        utb, xpwb + (size_t)l*128*Im, xdbl, nullptr, TOK, 128, Im, Im, Im, 128);
    k_gemm<3><<<dim3(Im/128, TOK/128), 256, 0, stream>>>(
        xdbl, dtwb + (size_t)l*Im*64, dtq, dtb + (size_t)l*Im, TOK, Im, 64, 128, 64, Im);
    // chunked scan (Q rows [0,QROWS), Hin rows [QROWS,2*QROWS) in proj u-columns)
    k_scan1<<<dim3(Im/256, Bt, NC), 256, 0, stream>>>(
        dtq, utb, xdbl, alog + (size_t)l*Im*Nst, proj, S);
    k_scan2<<<(Bt*Nst*Im)/256, 256, 0, stream>>>(
        proj, S, alog + (size_t)l*Im*Nst, proj);
    k_scan3<<<dim3(Im/256, Bt, NC), 256, 0, stream>>>(
        dtq, utb, xdbl, proj, alog + (size_t)l*Im*Nst, dpar + (size_t)l*Im, proj, yb);
    k_gemm256n<<<dim3(Dm/256, TOK/128), 512, 0, stream>>>(
        yb, outwb + (size_t)l*Dm*Im, h, TOK, Dm, Im, Im, Im, Dm);
  }

  k_rms_last<<<Bt, 256, 0, stream>>>(h, normf, xf);
  k_logits<<<Vv/4, 256, 0, stream>>>(xf, emb, out);
}

// Round 10
// 1272.193 us; speedup vs baseline: 1.0396x; 1.0396x over previous
//
#include <hip/hip_runtime.h>
#include <hip/hip_bf16.h>

#define Vv 32000
#define Dm 768
#define Lm 4
#define Nst 16
#define Kc 4
#define Im 1536
#define DTr 48
#define Bt 4
#define Sq 2048
#define TOK (Bt*Sq)
#define EPSf 1e-5f
#define NC 64              // time chunks
#define CL 32              // chunk length = Sq/NC
#define QROWS (Bt*NC*16)   // 4096 rows of Q; Hin rows [QROWS, 2*QROWS)
#define LOG2E 1.4426950408889634f
#define LN2f  0.6931471805599453f

using bf16 = __hip_bfloat16;
typedef __bf16 bf16x8 __attribute__((ext_vector_type(8)));
typedef float f32x4 __attribute__((ext_vector_type(4)));
typedef float f32x2 __attribute__((ext_vector_type(2)));

__device__ __forceinline__ float b2f(bf16 x){ return __bfloat162float(x); }
__device__ __forceinline__ bf16 f2b(float x){ return __float2bfloat16(x); }
__device__ __forceinline__ float us2f(ushort u){ unsigned x = (unsigned)u << 16; return __builtin_bit_cast(float, x); }

// raw v_exp_f32: args always in (-60, 20] here, no denormal guard needed
__device__ __forceinline__ float ex2(float x){
#if __has_builtin(__builtin_amdgcn_exp2f)
  return __builtin_amdgcn_exp2f(x);
#else
  float r; asm("v_exp_f32 %0, %1" : "=v"(r) : "v"(x)); return r;
#endif
}
__device__ __forceinline__ float vlog2(float x){
#if __has_builtin(__builtin_amdgcn_logf)
  return __builtin_amdgcn_logf(x);
#else
  float r; asm("v_log_f32 %0, %1" : "=v"(r) : "v"(x)); return r;
#endif
}
__device__ __forceinline__ float frcp(float x){
#if __has_builtin(__builtin_amdgcn_rcpf)
  return __builtin_amdgcn_rcpf(x);
#else
  float r; asm("v_rcp_f32 %0, %1" : "=v"(r) : "v"(x)); return r;
#endif
}

#define GLDS(gp, lp) __builtin_amdgcn_global_load_lds( \
    (const __attribute__((address_space(1))) void*)(gp), \
    (__attribute__((address_space(3))) void*)(lp), 16, 0, 0)

// ---------------- f32 -> bf16 weight conversion (n multiple of 1024) --------
__global__ __launch_bounds__(256) void k_cvt(const float* __restrict__ src,
                                             bf16* __restrict__ dst, int n){
  int i = (blockIdx.x*256 + threadIdx.x)*4;
  if (i >= n) return;
  float4 v = *(const float4*)(src + i);
  bf16* o = dst + i;
  o[0]=f2b(v.x); o[1]=f2b(v.y); o[2]=f2b(v.z); o[3]=f2b(v.w);
}

// x_proj_w (L,80,Im) f32 -> (L,128,Im) bf16, rows 80..127 zero
__global__ __launch_bounds__(256) void k_cvt_xpw(const float* __restrict__ src,
                                                 bf16* __restrict__ dst){
  int idx = blockIdx.x*256 + threadIdx.x;
  int l = idx / (128*Im); int rem = idx - l*128*Im;
  int r = rem / Im;       int c = rem - r*Im;
  dst[idx] = (r < 80) ? f2b(src[((size_t)l*80 + r)*Im + c]) : f2b(0.f);
}

// dt_proj_w (L,Im,48) f32 -> (L,Im,64) bf16, cols 48..63 zero
__global__ __launch_bounds__(256) void k_cvt_dtw(const float* __restrict__ src,
                                                 bf16* __restrict__ dst){
  int idx = blockIdx.x*256 + threadIdx.x;
  int l = idx / (Im*64); int rem = idx - l*Im*64;
  int r = rem / 64;      int c = rem - r*64;
  dst[idx] = (c < 48) ? f2b(src[((size_t)l*Im + r)*48 + c]) : f2b(0.f);
}

// ---------------- embedding gather ------------------------------------------
__global__ __launch_bounds__(256) void k_embed(const int* __restrict__ ids,
                                               const float* __restrict__ emb,
                                               float* __restrict__ h){
  int t = blockIdx.x;
  const float4* e = (const float4*)(emb + (size_t)ids[t]*Dm);
  float4* o = (float4*)(h + (size_t)t*Dm);
  if (threadIdx.x < Dm/4) o[threadIdx.x] = e[threadIdx.x];
}

// ---------------- rmsnorm ---------------------------------------------------
__global__ __launch_bounds__(256) void k_rmsnorm(const float* __restrict__ h,
                                                 const float* __restrict__ w,
                                                 bf16* __restrict__ xb){
  int t = blockIdx.x;
  const float* x = h + (size_t)t*Dm;
  float v[3]; float ss = 0.f;
  #pragma unroll
  for (int j=0;j<3;j++){ v[j] = x[threadIdx.x + j*256]; ss += v[j]*v[j]; }
  #pragma unroll
  for (int off=32; off; off>>=1) ss += __shfl_xor(ss, off);
  __shared__ float sred[4];
  int wave = threadIdx.x>>6, lane = threadIdx.x&63;
  if (lane==0) sred[wave]=ss;
  __syncthreads();
  float tot = sred[0]+sred[1]+sred[2]+sred[3];
  float scale = rsqrtf(tot*(1.f/Dm) + EPSf);
  bf16* o = xb + (size_t)t*Dm;
  #pragma unroll
  for (int j=0;j<3;j++){ int d = threadIdx.x + j*256; o[d] = f2b(v[j]*scale*w[d]); }
}

__global__ __launch_bounds__(256) void k_rms_last(const float* __restrict__ h,
                                                  const float* __restrict__ w,
                                                  float* __restrict__ xf){
  int b = blockIdx.x;
  const float* x = h + ((size_t)b*Sq + (Sq-1))*Dm;
  float v[3]; float ss = 0.f;
  #pragma unroll
  for (int j=0;j<3;j++){ v[j] = x[threadIdx.x + j*256]; ss += v[j]*v[j]; }
  #pragma unroll
  for (int off=32; off; off>>=1) ss += __shfl_xor(ss, off);
  __shared__ float sred[4];
  int wave = threadIdx.x>>6, lane = threadIdx.x&63;
  if (lane==0) sred[wave]=ss;
  __syncthreads();
  float tot = sred[0]+sred[1]+sred[2]+sred[3];
  float scale = rsqrtf(tot*(1.f/Dm) + EPSf);
  float* o = xf + (size_t)b*Dm;
  #pragma unroll
  for (int j=0;j<3;j++){ int d = threadIdx.x + j*256; o[d] = v[j]*scale*w[d]; }
}

// ---------------- MFMA bf16 GEMM 128x128 (dt) -------------------------------
// MODE 0: bf16 out; MODE 1: f32 +=; MODE 3: softplus(x+bias) -> bf16
template<int MODE>
__global__ __launch_bounds__(256) void k_gemm(const bf16* __restrict__ A,
                                              const bf16* __restrict__ Bw,
                                              void* __restrict__ Cout,
                                              const float* __restrict__ bias,
                                              int M, int N, int K,
                                              int lda, int ldb, int ldc){
  __shared__ __align__(16) ushort Ash[128*32];
  __shared__ __align__(16) ushort Bsh[128*32];
  int tid = threadIdx.x;
  int bm = blockIdx.y, bn = blockIdx.x;
  int wave = tid >> 6, lane = tid & 63;
  int wrow = wave >> 1, wcol = wave & 1;
  int quad = lane >> 4, lq = lane & 15;

  f32x4 acc[4][4];
  #pragma unroll
  for (int a=0;a<4;a++)
    #pragma unroll
    for (int b=0;b<4;b++) acc[a][b] = (f32x4){0.f,0.f,0.f,0.f};

  const ushort* Ag = (const ushort*)A;
  const ushort* Bg = (const ushort*)Bw;

  for (int k0 = 0; k0 < K; k0 += 32) {
    __syncthreads();
    #pragma unroll
    for (int c = tid; c < 512; c += 256) {
      int row = c >> 2, col = (c & 3) * 8;
      GLDS(&Ag[(size_t)(bm*128 + row)*lda + k0 + col], &Ash[c*8]);
      GLDS(&Bg[(size_t)(bn*128 + row)*ldb + k0 + col], &Bsh[c*8]);
    }
    __syncthreads();
    bf16x8 af[4], bfr[4];
    #pragma unroll
    for (int a=0;a<4;a++){
      int m = wrow*64 + a*16 + lq;
      af[a] = __builtin_bit_cast(bf16x8, *(const uint4*)&Ash[m*32 + quad*8]);
    }
    #pragma unroll
    for (int b=0;b<4;b++){
      int n = wcol*64 + b*16 + lq;
      bfr[b] = __builtin_bit_cast(bf16x8, *(const uint4*)&Bsh[n*32 + quad*8]);
    }
    #pragma unroll
    for (int a=0;a<4;a++)
      #pragma unroll
      for (int b=0;b<4;b++)
        acc[a][b] = __builtin_amdgcn_mfma_f32_16x16x32_bf16(af[a], bfr[b], acc[a][b], 0, 0, 0);
  }
  #pragma unroll
  for (int a=0;a<4;a++)
    #pragma unroll
    for (int b=0;b<4;b++)
      #pragma unroll
      for (int r=0;r<4;r++){
        int row = bm*128 + wrow*64 + a*16 + quad*4 + r;
        int col = bn*128 + wcol*64 + b*16 + lq;
        size_t idx = (size_t)row*ldc + col;
        if (MODE == 0) ((bf16*)Cout)[idx] = f2b(acc[a][b][r]);
        else if (MODE == 1) ((float*)Cout)[idx] += acc[a][b][r];
        else {
          // softplus via raw v_exp/v_log, stored bf16 (dt)
          float v = acc[a][b][r] + bias[col];
          float sp;
          if (v > 20.f) sp = v;
          else { float e = ex2(v*LOG2E); sp = vlog2(1.f + e)*LN2f; }
          ((bf16*)Cout)[idx] = f2b(sp);
        }
      }
}

// ---------------- MFMA bf16 GEMM 64x128 (x_proj) ----------------------------
// R9 lesson: x_proj at BM=128 launches only 128 blocks (N=128 -> 1 col-block),
// half the machine idle. BM=64 doubles the grid to 256 blocks. A-tile staging
// is exactly ONE global_load_lds per k-step (64x32 = 256 lanes x 16B).
__global__ __launch_bounds__(256) void k_gemm64(const bf16* __restrict__ A,
                                                const bf16* __restrict__ Bw,
                                                bf16* __restrict__ Cout,
                                                int M, int N, int K,
                                                int lda, int ldb, int ldc){
  __shared__ __align__(16) ushort Ash[64*32];
  __shared__ __align__(16) ushort Bsh[128*32];
  int tid = threadIdx.x;
  int bm = blockIdx.y, bn = blockIdx.x;
  int wave = tid >> 6, lane = tid & 63;
  int wrow = wave >> 1, wcol = wave & 1;
  int quad = lane >> 4, lq = lane & 15;

  f32x4 acc[2][4];
  #pragma unroll
  for (int a=0;a<2;a++)
    #pragma unroll
    for (int b=0;b<4;b++) acc[a][b] = (f32x4){0.f,0.f,0.f,0.f};

  const ushort* Ag = (const ushort*)A;
  const ushort* Bg = (const ushort*)Bw;

  for (int k0 = 0; k0 < K; k0 += 32) {
    __syncthreads();
    {
      int row = tid >> 2, col = (tid & 3) * 8;
      GLDS(&Ag[(size_t)(bm*64 + row)*lda + k0 + col], &Ash[tid*8]);
    }
    #pragma unroll
    for (int c = tid; c < 512; c += 256) {
      int row = c >> 2, col = (c & 3) * 8;
      GLDS(&Bg[(size_t)(bn*128 + row)*ldb + k0 + col], &Bsh[c*8]);
    }
    __syncthreads();
    bf16x8 af[2], bfr[4];
    #pragma unroll
    for (int a=0;a<2;a++){
      int m = wrow*32 + a*16 + lq;
      af[a] = __builtin_bit_cast(bf16x8, *(const uint4*)&Ash[m*32 + quad*8]);
    }
    #pragma unroll
    for (int b=0;b<4;b++){
      int n = wcol*64 + b*16 + lq;
      bfr[b] = __builtin_bit_cast(bf16x8, *(const uint4*)&Bsh[n*32 + quad*8]);
    }
    #pragma unroll
    for (int a=0;a<2;a++)
      #pragma unroll
      for (int b=0;b<4;b++)
        acc[a][b] = __builtin_amdgcn_mfma_f32_16x16x32_bf16(af[a], bfr[b], acc[a][b], 0, 0, 0);
  }
  #pragma unroll
  for (int a=0;a<2;a++)
    #pragma unroll
    for (int b=0;b<4;b++)
      #pragma unroll
      for (int r=0;r<4;r++){
        int row = bm*64 + wrow*32 + a*16 + quad*4 + r;
        int col = bn*128 + wcol*64 + b*16 + lq;
        Cout[(size_t)row*ldc + col] = f2b(acc[a][b][r]);
      }
}

// ---------------- MFMA bf16 GEMM 256x256 8-phase (in_proj) -------------------
// BM=BN=256, BK=64, 512 threads = 8 waves (2M x 4N), per-wave 128x64 output.
// LDS 128KB: A[2][256][64] bf16 at 0, B[2][256][64] at 65536. Swizzle:
// storage_byte = (r<<7) + (colbyte ^ ((r&7)<<4)); GLDS dest linear, XOR
// pre-applied on the per-lane GLOBAL source (rule #21).
// Register-resident fragments -> 24 ds_read_b128/tile (minimum).
// vmcnt(4) at P1,P2,P4 covers each unit's deadline. Never vmcnt(0) mid-loop.
// Requires grid >= ~2x256 blocks (1 block/CU at 128KB LDS): in_proj only.
#define SA256(qm,k0s,bf_) { GLDS(Ag + sA[qm][0] + (k0s), lds + (bf_)*32768 + lA[qm][0]); \
                            GLDS(Ag + sA[qm][1] + (k0s), lds + (bf_)*32768 + lA[qm][1]); }
#define SB256(qn,k0s,bf_) { GLDS(Bg + sB[qn][0] + (k0s), lds + 65536 + (bf_)*32768 + lB[qn][0]); \
                            GLDS(Bg + sB[qn][1] + (k0s), lds + 65536 + (bf_)*32768 + lB[qn][1]); }
#define RD_A(qm_) do{ _Pragma("unroll") for(int m2=0;m2<4;m2++){ \
    int r = wm*128 + ((qm_)*4+m2)*16 + lq; \
    _Pragma("unroll") for(int kh=0;kh<2;kh++) \
      bA[m2][kh] = *(const uint4*)(Ab + (r<<7) + ((kh*64 + quad*16) ^ ((r&7)<<4))); } }while(0)
#define RD_B(qn_) do{ _Pragma("unroll") for(int n2=0;n2<2;n2++){ \
    int r = wn*64 + ((qn_)*2+n2)*16 + lq; \
    _Pragma("unroll") for(int kh=0;kh<2;kh++) \
      bB[qn_][n2][kh] = *(const uint4*)(Bb + (r<<7) + ((kh*64 + quad*16) ^ ((r&7)<<4))); } }while(0)
#define MMA256(qm_,qn_) do{ \
  __builtin_amdgcn_s_barrier(); \
  __builtin_amdgcn_sched_barrier(0); \
  __builtin_amdgcn_s_setprio(1); \
  _Pragma("unroll") for(int m2=0;m2<4;m2++) \
    _Pragma("unroll") for(int n2=0;n2<2;n2++) \
      _Pragma("unroll") for(int kh=0;kh<2;kh++) \
        acc[(qm_)*4+m2][(qn_)*2+n2] = __builtin_amdgcn_mfma_f32_16x16x32_bf16( \
          __builtin_bit_cast(bf16x8, bA[m2][kh]), __builtin_bit_cast(bf16x8, bB[qn_][n2][kh]), \
          acc[(qm_)*4+m2][(qn_)*2+n2], 0, 0, 0); \
  __builtin_amdgcn_s_setprio(0); \
  __builtin_amdgcn_s_barrier(); \
  __builtin_amdgcn_sched_barrier(0); \
}while(0)
#define VMW4 asm volatile("s_waitcnt vmcnt(4)":::"memory")

template<int MODE>
__global__ __launch_bounds__(512, 2) void k_gemm256(const bf16* __restrict__ A,
                                                    const bf16* __restrict__ Bw,
                                                    void* __restrict__ Cout,
                                                    int M, int N, int K,
                                                    int lda, int ldb, int ldc){
  __shared__ __align__(16) char lds[131072];
  int tid = threadIdx.x;
  int wave = tid >> 6, lane = tid & 63;
  int wm = wave >> 2, wn = wave & 3;
  int quad = lane >> 4, lq = lane & 15;
  // XCD-aware bijective swizzle (T1)
  int nx = gridDim.x;
  int nwg = nx * gridDim.y;
  int lin = blockIdx.y * nx + blockIdx.x;
  if ((nwg & 7) == 0){
    int cpx = nwg >> 3;
    lin = (lin & 7)*cpx + (lin >> 3);
  }
  int bm = lin / nx, bn = lin - bm*nx;
  const ushort* Ag = (const ushort*)A;
  const ushort* Bg = (const ushort*)Bw;

  size_t sA[2][2]; int lA[2][2];
  size_t sB[2][2]; int lB[2][2];
  #pragma unroll
  for (int qm=0; qm<2; qm++)
    #pragma unroll
    for (int d=0; d<2; d++){
      int r = d*128 + qm*64 + (tid>>3);
      int cb = ((tid&7)<<4) ^ ((r&7)<<4);
      sA[qm][d] = (size_t)(bm*256 + r)*lda + (cb>>1);
      lA[qm][d] = ((d*128 + qm*64)<<7) + tid*16;
    }
  #pragma unroll
  for (int qn=0; qn<2; qn++)
    #pragma unroll
    for (int d=0; d<2; d++){
      int g = 2*d + (wave>>2);
      int jj = tid & 255;
      int r = g*64 + qn*32 + (jj>>3);
      int cb = ((jj&7)<<4) ^ ((r&7)<<4);
      sB[qn][d] = (size_t)(bn*256 + r)*ldb + (cb>>1);
      lB[qn][d] = ((g*64 + qn*32)<<7) + jj*16;
    }

  f32x4 acc[8][4];
  #pragma unroll
  for (int a=0;a<8;a++)
    #pragma unroll
    for (int b=0;b<4;b++) acc[a][b] = (f32x4){0.f,0.f,0.f,0.f};

  SA256(0, 0, 0); SB256(0, 0, 0); SB256(1, 0, 0); SA256(1, 0, 0);
  VMW4;
  __builtin_amdgcn_s_barrier();
  __builtin_amdgcn_sched_barrier(0);

  uint4 bA[4][2], bB[2][2][2];
  int NT = K >> 6;
  for (int t = 0; t < NT-1; t++){
    int buf = t & 1, bufn = buf ^ 1;
    int k0n = (t+1) << 6;
    const char* Ab = lds + buf*32768;
    const char* Bb = lds + 65536 + buf*32768;
    RD_A(0); RD_B(0); SA256(0,k0n,bufn); VMW4; MMA256(0,0);
    RD_B(1);          SB256(0,k0n,bufn); VMW4; MMA256(0,1);
    RD_A(1);          SB256(1,k0n,bufn);       MMA256(1,0);
                      SA256(1,k0n,bufn); VMW4; MMA256(1,1);
  }
  {
    int buf = (NT-1) & 1;
    const char* Ab = lds + buf*32768;
    const char* Bb = lds + 65536 + buf*32768;
    RD_A(0); RD_B(0); asm volatile("s_waitcnt vmcnt(2)":::"memory"); MMA256(0,0);
    RD_B(1);          asm volatile("s_waitcnt vmcnt(0)":::"memory"); MMA256(0,1);
    RD_A(1);                                                          MMA256(1,0);
                                                                      MMA256(1,1);
  }

  #pragma unroll
  for (int mr=0; mr<8; mr++)
    #pragma unroll
    for (int nr=0; nr<4; nr++)
      #pragma unroll
      for (int rr=0; rr<4; rr++){
        int row = bm*256 + wm*128 + mr*16 + quad*4 + rr;
        int col = bn*256 + wn*64 + nr*16 + lq;
        size_t idx = (size_t)row*ldc + col;
        if (MODE == 0) ((bf16*)Cout)[idx] = f2b(acc[mr][nr][rr]);
        else ((float*)Cout)[idx] += acc[mr][nr][rr];
      }
}

// ------- MFMA bf16 GEMM 128x256 4-phase (out_proj, f32 +=) -------------------
// BM=128 x BN=256 -> 384 blocks (1.5 rounds of 256 CUs). 8 waves = 1M x 8N.
// LDS 96KB: A[2][128][64] at 0, B[2][256][64] at 32768. FIFO deadlines:
// vmcnt(5)@P2 covers P3's A1 reads; vmcnt(1)@P4 covers next tile's P1 reads.
#define SAn(qm_,k0s,bf_) GLDS(Ag + snA[qm_] + (k0s), lds + (bf_)*16384 + lnA[qm_])
#define SBn(k0s,bf_) { GLDS(Bg + snB[0] + (k0s), lds + 32768 + (bf_)*32768 + lnB[0]); \
                       GLDS(Bg + snB[1] + (k0s), lds + 32768 + (bf_)*32768 + lnB[1]); \
                       GLDS(Bg + snB[2] + (k0s), lds + 32768 + (bf_)*32768 + lnB[2]); \
                       GLDS(Bg + snB[3] + (k0s), lds + 32768 + (bf_)*32768 + lnB[3]); }
#define RDAn(h_) do{ _Pragma("unroll") for(int mf=0; mf<4; mf++){ \
    int r = ((h_)*4+mf)*16 + lq; \
    _Pragma("unroll") for(int kh=0;kh<2;kh++) \
      bA[mf][kh] = *(const uint4*)(Ab + (r<<7) + ((kh*64 + quad*16) ^ ((r&7)<<4))); } }while(0)
#define RDBn() do{ _Pragma("unroll") for(int n2=0;n2<2;n2++){ \
    int r = wn*32 + n2*16 + lq; \
    _Pragma("unroll") for(int kh=0;kh<2;kh++) \
      bB[n2][kh] = *(const uint4*)(Bb + (r<<7) + ((kh*64 + quad*16) ^ ((r&7)<<4))); } }while(0)
#define MMAn(h_,s_) do{ \
  __builtin_amdgcn_s_barrier(); \
  __builtin_amdgcn_sched_barrier(0); \
  __builtin_amdgcn_s_setprio(1); \
  _Pragma("unroll") for(int m2=0;m2<2;m2++) \
    _Pragma("unroll") for(int n2=0;n2<2;n2++) \
      _Pragma("unroll") for(int kh=0;kh<2;kh++) \
        acc[(h_)*4+(s_)*2+m2][n2] = __builtin_amdgcn_mfma_f32_16x16x32_bf16( \
          __builtin_bit_cast(bf16x8, bA[(s_)*2+m2][kh]), __builtin_bit_cast(bf16x8, bB[n2][kh]), \
          acc[(h_)*4+(s_)*2+m2][n2], 0, 0, 0); \
  __builtin_amdgcn_s_setprio(0); \
  __builtin_amdgcn_s_barrier(); \
  __builtin_amdgcn_sched_barrier(0); \
}while(0)

__global__ __launch_bounds__(512, 2) void k_gemm256n(const bf16* __restrict__ A,
                                                     const bf16* __restrict__ Bw,
                                                     float* __restrict__ Cout,
                                                     int M, int N, int K,
                                                     int lda, int ldb, int ldc){
  __shared__ __align__(16) char lds[98304];
  int tid = threadIdx.x;
  int wave = tid >> 6, lane = tid & 63;
  int wn = wave;                          // 8 waves across N
  int quad = lane >> 4, lq = lane & 15;
  // XCD-aware bijective swizzle (nwg = 384, %8 == 0)
  int nx = gridDim.x;
  int nwg = nx * gridDim.y;
  int lin = blockIdx.y * nx + blockIdx.x;
  if ((nwg & 7) == 0){
    int cpx = nwg >> 3;
    lin = (lin & 7)*cpx + (lin >> 3);
  }
  int bm = lin / nx, bn = lin - bm*nx;
  const ushort* Ag = (const ushort*)A;
  const ushort* Bg = (const ushort*)Bw;

  size_t snA[2]; int lnA[2];
  size_t snB[4]; int lnB[4];
  #pragma unroll
  for (int qm=0; qm<2; qm++){
    int r = qm*64 + (tid>>3);
    int cb = ((tid&7)<<4) ^ ((r&7)<<4);
    snA[qm] = (size_t)(bm*128 + r)*lda + (cb>>1);
    lnA[qm] = qm*8192 + tid*16;
  }
  #pragma unroll
  for (int d=0; d<4; d++){
    int r = d*64 + (tid>>3);
    int cb = ((tid&7)<<4) ^ ((r&7)<<4);
    snB[d] = (size_t)(bn*256 + r)*ldb + (cb>>1);
    lnB[d] = d*8192 + tid*16;
  }

  f32x4 acc[8][2];
  #pragma unroll
  for (int a=0;a<8;a++){ acc[a][0] = (f32x4){0.f,0.f,0.f,0.f}; acc[a][1] = (f32x4){0.f,0.f,0.f,0.f}; }

  // prologue: FIFO = B(4), A0(1), A1(1); wait through A0 (allow A1 outstanding)
  SBn(0, 0); SAn(0, 0, 0); SAn(1, 0, 0);
  asm volatile("s_waitcnt vmcnt(1)":::"memory");
  __builtin_amdgcn_s_barrier();
  __builtin_amdgcn_sched_barrier(0);

  uint4 bA[4][2], bB[2][2];
  int NT = K >> 6;
  for (int t = 0; t < NT-1; t++){
    int buf = t & 1, bufn = buf ^ 1;
    int k0n = (t+1) << 6;
    const char* Ab = lds + buf*16384;
    const char* Bb = lds + 32768 + buf*32768;
    RDAn(0); RDBn(); SBn(k0n,bufn); SAn(0,k0n,bufn);                        MMAn(0,0);
    asm volatile("s_waitcnt vmcnt(5)":::"memory");                          MMAn(0,1);
    RDAn(1); SAn(1,k0n,bufn);                                               MMAn(1,0);
    asm volatile("s_waitcnt vmcnt(1)":::"memory");                          MMAn(1,1);
  }
  { // tail tile
    int buf = (NT-1) & 1;
    const char* Ab = lds + buf*16384;
    const char* Bb = lds + 32768 + buf*32768;
    RDAn(0); RDBn();                                                        MMAn(0,0);
    asm volatile("s_waitcnt vmcnt(0)":::"memory");                          MMAn(0,1);
    RDAn(1);                                                                MMAn(1,0);
                                                                            MMAn(1,1);
  }

  #pragma unroll
  for (int mf=0; mf<8; mf++)
    #pragma unroll
    for (int n2=0; n2<2; n2++)
      #pragma unroll
      for (int rr=0; rr<4; rr++){
        int row = bm*128 + mf*16 + quad*4 + rr;
        int col = bn*256 + wn*32 + n2*16 + lq;
        Cout[(size_t)row*ldc + col] += acc[mf][n2][rr];
      }
}

// ------ depthwise causal conv K=4 + bias + SiLU, 8 channels/thread ----------
__global__ __launch_bounds__(192) void k_conv8(const bf16* __restrict__ proj,
                                               const float* __restrict__ cw,
                                               const float* __restrict__ cb,
                                               bf16* __restrict__ ut){
  int t = blockIdx.x;
  int i = threadIdx.x*8;                       // 192*8 = 1536 = Im
  int s = t & (Sq-1);
  float acc[8];
  {
    float4 b0 = *(const float4*)(cb + i);
    float4 b1 = *(const float4*)(cb + i + 4);
    acc[0]=b0.x; acc[1]=b0.y; acc[2]=b0.z; acc[3]=b0.w;
    acc[4]=b1.x; acc[5]=b1.y; acc[6]=b1.z; acc[7]=b1.w;
  }
  float4 w[8];
  #pragma unroll
  for (int j=0;j<8;j++) w[j] = *(const float4*)(cw + (size_t)(i+j)*4);
  const ushort* pr = (const ushort*)proj + (size_t)t*(2*Im) + i;
  if (s >= 3){
    #pragma unroll
    for (int k=0;k<Kc;k++){
      uint4 v = *(const uint4*)(pr + (ptrdiff_t)(k-3)*(2*Im));
      const ushort* u = (const ushort*)&v;
      #pragma unroll
      for (int j=0;j<8;j++) acc[j] += us2f(u[j]) * (&w[j].x)[k];
    }
  } else {
    #pragma unroll
    for (int k=0;k<Kc;k++){
      if (s + k - 3 >= 0){
        uint4 v = *(const uint4*)(pr + (ptrdiff_t)(k-3)*(2*Im));
        const ushort* u = (const ushort*)&v;
        #pragma unroll
        for (int j=0;j<8;j++) acc[j] += us2f(u[j]) * (&w[j].x)[k];
      }
    }
  }
  ushort o[8];
  #pragma unroll
  for (int j=0;j<8;j++){
    float sig = frcp(1.f + ex2(-acc[j]*LOG2E));
    o[j] = __builtin_bit_cast(ushort, f2b(acc[j]*sig));
  }
  *(uint4*)((ushort*)ut + (size_t)t*Im + i) = *(const uint4*)o;
}

// ============ chunked selective scan: thread per (b,i,chunk), 16 states/thread
// Q (rows [0,QROWS)) and Hin (rows [QROWS,2*QROWS)) live in dead u-columns of proj.
// FAST DECAY PATH: kn[n] == (n+1)*kn[0] (this model's A_log) -> decays are
// p^(n+1), 1 transcendental + packed-f32 power tree. Runtime-guarded.
// (R9 lesson: bulk LDS staging of dt/ut/gate was neutral-negative; the R8
// global-load + 2-step-prefetch form is kept.)

// pass1: per-chunk local scan from h=0 -> Q (h_end, bf16), S (sum dt, f32)
__global__ __launch_bounds__(256) void k_scan1(const bf16* __restrict__ dt,
                                               const bf16* __restrict__ ut,
                                               const bf16* __restrict__ xdbl,
                                               const float* __restrict__ alog,
                                               bf16* __restrict__ Qb,   // proj base
                                               float* __restrict__ S){
  __shared__ float s_b[CL][16];                  // 2 KB: B per step
  int tid = threadIdx.x;
  int i = blockIdx.x*256 + tid;
  int b = blockIdx.y, c = blockIdx.z;
  size_t tok0 = (size_t)b*Sq + c*CL;
  {
    int row = tid >> 1, part = tid & 1;
    if (row < CL){
      uint4 v = *(const uint4*)((const ushort*)xdbl + (tok0+row)*128 + 48 + part*8);
      const ushort* u = (const ushort*)&v;
      #pragma unroll
      for (int j=0;j<8;j++) s_b[row][part*8+j] = us2f(u[j]);
    }
  }
  float kn[16];
  {
    const float4* ap = (const float4*)(alog + (size_t)i*16);
    #pragma unroll
    for (int q=0;q<4;q++){
      float4 a4 = ap[q];
      kn[q*4+0] = -__expf(a4.x)*LOG2E; kn[q*4+1] = -__expf(a4.y)*LOG2E;
      kn[q*4+2] = -__expf(a4.z)*LOG2E; kn[q*4+3] = -__expf(a4.w)*LOG2E;
    }
  }
  bool fastp = true;
  #pragma unroll
  for (int n=1;n<16;n++)
    fastp = fastp && (fabsf(kn[n] - (float)(n+1)*kn[0]) <= 1e-4f*fabsf(kn[n]));
  __syncthreads();
  float sum = 0.f;
  const ushort* dtp = (const ushort*)dt + tok0*Im + i;
  const ushort* utp = (const ushort*)ut + tok0*Im + i;
  ushort dA = dtp[0], uA = utp[0];
  ushort dB = dtp[Im], uB = utp[Im];             // CL >= 2
  int rq = (b*NC + c)*16;
  if (fastp){
    float k0 = kn[0];
    f32x2 h2[8];
    #pragma unroll
    for (int j=0;j<8;j++) h2[j] = (f32x2){0.f,0.f};
    for (int t = 0; t < CL; t++){
      float dtv = us2f(dA); float uv = us2f(uA);
      dA = dB; uA = uB;
      if (t+2 < CL){
        dB = dtp[(size_t)(t+2)*Im];
        uB = utp[(size_t)(t+2)*Im];
      }
      sum += dtv;
      float cdu = dtv*uv;
      f32x2 cdu2 = (f32x2){cdu, cdu};
      const f32x4* brow = (const f32x4*)&s_b[t][0];
      f32x4 B0=brow[0], B1=brow[1], B2=brow[2], B3=brow[3];
      f32x2 Bv2[8] = {
        __builtin_shufflevector(B0,B0,0,1), __builtin_shufflevector(B0,B0,2,3),
        __builtin_shufflevector(B1,B1,0,1), __builtin_shufflevector(B1,B1,2,3),
        __builtin_shufflevector(B2,B2,0,1), __builtin_shufflevector(B2,B2,2,3),
        __builtin_shufflevector(B3,B3,0,1), __builtin_shufflevector(B3,B3,2,3)};
      float p1 = ex2(k0*dtv);
      float p2 = p1*p1;
      f32x2 d2[8];
      d2[0] = (f32x2){p1,p2};
      f32x2 pp = (f32x2){p2,p2};
      d2[1] = d2[0]*pp;                       // p3,p4
      pp = (f32x2){d2[1][1], d2[1][1]};
      d2[2] = d2[0]*pp;                       // p5,p6
      d2[3] = d2[1]*pp;                       // p7,p8
      pp = (f32x2){d2[3][1], d2[3][1]};
      d2[4]=d2[0]*pp; d2[5]=d2[1]*pp; d2[6]=d2[2]*pp; d2[7]=d2[3]*pp;
      #pragma unroll
      for (int j=0;j<8;j++)
        h2[j] = d2[j]*h2[j] + cdu2*Bv2[j];
    }
    #pragma unroll
    for (int n=0;n<16;n++)
      Qb[(size_t)(rq+n)*2*Im + i] = f2b(h2[n>>1][n&1]);
  } else {
    float h[16];
    #pragma unroll
    for (int n=0;n<16;n++) h[n]=0.f;
    for (int t = 0; t < CL; t++){
      float dtv = us2f(dA); float uv = us2f(uA);
      dA = dB; uA = uB;
      if (t+2 < CL){
        dB = dtp[(size_t)(t+2)*Im];
        uB = utp[(size_t)(t+2)*Im];
      }
      sum += dtv;
      float cdu = dtv*uv;
      const f32x4* brow = (const f32x4*)&s_b[t][0];
      f32x4 B0=brow[0], B1=brow[1], B2=brow[2], B3=brow[3];
      float Bv[16] = {B0[0],B0[1],B0[2],B0[3],B1[0],B1[1],B1[2],B1[3],
                      B2[0],B2[1],B2[2],B2[3],B3[0],B3[1],B3[2],B3[3]};
      #pragma unroll
      for (int n=0;n<16;n++)
        h[n] = ex2(kn[n]*dtv)*h[n] + cdu*Bv[n];
    }
    #pragma unroll
    for (int n=0;n<16;n++)
      Qb[(size_t)(rq+n)*2*Im + i] = f2b(h[n]);
  }
  S[(size_t)(b*NC + c)*Im + i] = sum;
}

// pass2: stitch chunks: Hin[c] = h before chunk c
__global__ __launch_bounds__(256) void k_scan2(const bf16* __restrict__ Qb,
                                               const float* __restrict__ S,
                                               const float* __restrict__ alog,
                                               bf16* __restrict__ Hinb){
  int idx = blockIdx.x*256 + threadIdx.x;        // (b,n,i)
  int i = idx % Im; int bn = idx / Im;
  int n = bn & 15, b = bn >> 4;
  float kn = -__expf(alog[(size_t)i*16 + n])*LOG2E;
  float h = 0.f;
  for (int c = 0; c < NC; c++){
    size_t r = (size_t)((b*NC + c)*16 + n);
    Hinb[(QROWS + r)*2*Im + i] = f2b(h);
    float P = ex2(kn * S[(size_t)(b*NC + c)*Im + i]);
    h = P*h + b2f(Qb[r*2*Im + i]);
  }
}

// pass3: re-run chunk with h_in, produce y with fused epilogue
__global__ __launch_bounds__(256) void k_scan3(const bf16* __restrict__ dt,
                                               const bf16* __restrict__ ut,
                                               const bf16* __restrict__ xdbl,
                                               const bf16* __restrict__ proj,
                                               const float* __restrict__ alog,
                                               const float* __restrict__ dpar,
                                               const bf16* __restrict__ Hinb,
                                               bf16* __restrict__ y){
  __shared__ float s_bc[CL][32];                 // 4 KB: B|C per step
  int tid = threadIdx.x;
  int i = blockIdx.x*256 + tid;
  int b = blockIdx.y, c = blockIdx.z;
  size_t tok0 = (size_t)b*Sq + c*CL;
  {
    int row = tid >> 1, part = tid & 1;
    if (row < CL){
      const ushort* src = (const ushort*)xdbl + (tok0+row)*128 + 48 + part*16;
      uint4 v0 = *(const uint4*)src;
      uint4 v1 = *(const uint4*)(src + 8);
      const ushort* u0 = (const ushort*)&v0;
      const ushort* u1 = (const ushort*)&v1;
      #pragma unroll
      for (int j=0;j<8;j++){
        s_bc[row][part*16 + j]     = us2f(u0[j]);
        s_bc[row][part*16 + 8 + j] = us2f(u1[j]);
      }
    }
  }
  float kn[16];
  {
    const float4* ap = (const float4*)(alog + (size_t)i*16);
    #pragma unroll
    for (int q=0;q<4;q++){
      float4 a4 = ap[q];
      kn[q*4+0] = -__expf(a4.x)*LOG2E; kn[q*4+1] = -__expf(a4.y)*LOG2E;
      kn[q*4+2] = -__expf(a4.z)*LOG2E; kn[q*4+3] = -__expf(a4.w)*LOG2E;
    }
  }
  bool fastp = true;
  #pragma unroll
  for (int n=1;n<16;n++)
    fastp = fastp && (fabsf(kn[n] - (float)(n+1)*kn[0]) <= 1e-4f*fabsf(kn[n]));
  float Dp = dpar[i];
  int rq = QROWS + (b*NC + c)*16;
  __syncthreads();
  const ushort* dtp = (const ushort*)dt + tok0*Im + i;
  const ushort* utp = (const ushort*)ut + tok0*Im + i;
  const ushort* gp  = (const ushort*)proj + tok0*2*Im + Im + i;
  ushort dA = dtp[0], uA = utp[0], gA = gp[0];
  ushort dB = dtp[Im], uB = utp[Im], gB = gp[2*Im];
  if (fastp){
    float k0 = kn[0];
    f32x2 h2[8];
    #pragma unroll
    for (int j=0;j<8;j++)
      h2[j] = (f32x2){ b2f(Hinb[(size_t)(rq+2*j)*2*Im + i]),
                       b2f(Hinb[(size_t)(rq+2*j+1)*2*Im + i]) };
    for (int t = 0; t < CL; t++){
      float dtv = us2f(dA); float uv = us2f(uA); float g = us2f(gA);
      dA = dB; uA = uB; gA = gB;
      if (t+2 < CL){
        dB = dtp[(size_t)(t+2)*Im];
        uB = utp[(size_t)(t+2)*Im];
        gB = gp[(size_t)(t+2)*2*Im];
      }
      float cdu = dtv*uv;
      f32x2 cdu2 = (f32x2){cdu, cdu};
      const f32x4* brow = (const f32x4*)&s_bc[t][0];
      f32x4 B0=brow[0], B1=brow[1], B2=brow[2], B3=brow[3];
      f32x4 C0=brow[4], C1=brow[5], C2=brow[6], C3=brow[7];
      f32x2 Bv2[8] = {
        __builtin_shufflevector(B0,B0,0,1), __builtin_shufflevector(B0,B0,2,3),
        __builtin_shufflevector(B1,B1,0,1), __builtin_shufflevector(B1,B1,2,3),
        __builtin_shufflevector(B2,B2,0,1), __builtin_shufflevector(B2,B2,2,3),
        __builtin_shufflevector(B3,B3,0,1), __builtin_shufflevector(B3,B3,2,3)};
      f32x2 Cv2[8] = {
        __builtin_shufflevector(C0,C0,0,1), __builtin_shufflevector(C0,C0,2,3),
        __builtin_shufflevector(C1,C1,0,1), __builtin_shufflevector(C1,C1,2,3),
        __builtin_shufflevector(C2,C2,0,1), __builtin_shufflevector(C2,C2,2,3),
        __builtin_shufflevector(C3,C3,0,1), __builtin_shufflevector(C3,C3,2,3)};
      float p1 = ex2(k0*dtv);
      float p2 = p1*p1;
      f32x2 d2[8];
      d2[0] = (f32x2){p1,p2};
      f32x2 pp = (f32x2){p2,p2};
      d2[1] = d2[0]*pp;
      pp = (f32x2){d2[1][1], d2[1][1]};
      d2[2] = d2[0]*pp;
      d2[3] = d2[1]*pp;
      pp = (f32x2){d2[3][1], d2[3][1]};
      d2[4]=d2[0]*pp; d2[5]=d2[1]*pp; d2[6]=d2[2]*pp; d2[7]=d2[3]*pp;
      f32x2 yv2 = (f32x2){0.f, 0.f};
      #pragma unroll
      for (int j=0;j<8;j++){
        h2[j] = d2[j]*h2[j] + cdu2*Bv2[j];
        yv2 = yv2 + h2[j]*Cv2[j];
      }
      float yv = yv2[0] + yv2[1];
      float sig = frcp(1.f + ex2(-g*LOG2E));
      float outv = (yv + uv*Dp) * (g*sig);
      y[(tok0+t)*Im + i] = f2b(outv);
    }
  } else {
    float h[16];
    #pragma unroll
    for (int n=0;n<16;n++)
      h[n] = b2f(Hinb[(size_t)(rq+n)*2*Im + i]);
    for (int t = 0; t < CL; t++){
      float dtv = us2f(dA); float uv = us2f(uA); float g = us2f(gA);
      dA = dB; uA = uB; gA = gB;
      if (t+2 < CL){
        dB = dtp[(size_t)(t+2)*Im];
        uB = utp[(size_t)(t+2)*Im];
        gB = gp[(size_t)(t+2)*2*Im];
      }
      float cdu = dtv*uv;
      const f32x4* brow = (const f32x4*)&s_bc[t][0];
      f32x4 B0=brow[0], B1=brow[1], B2=brow[2], B3=brow[3];
      f32x4 C0=brow[4], C1=brow[5], C2=brow[6], C3=brow[7];
      float Bv[16] = {B0[0],B0[1],B0[2],B0[3],B1[0],B1[1],B1[2],B1[3],
                      B2[0],B2[1],B2[2],B2[3],B3[0],B3[1],B3[2],B3[3]};
      float Cv[16] = {C0[0],C0[1],C0[2],C0[3],C1[0],C1[1],C1[2],C1[3],
                      C2[0],C2[1],C2[2],C2[3],C3[0],C3[1],C3[2],C3[3]};
      float yv = 0.f;
      #pragma unroll
      for (int n=0;n<16;n++){
        h[n] = ex2(kn[n]*dtv)*h[n] + cdu*Bv[n];
        yv += h[n]*Cv[n];
      }
      float sig = frcp(1.f + ex2(-g*LOG2E));
      float outv = (yv + uv*Dp) * (g*sig);
      y[(tok0+t)*Im + i] = f2b(outv);
    }
  }
}

// ---------------- logits (f32 out) ------------------------------------------
__global__ __launch_bounds__(256) void k_logits(const float* __restrict__ xf,
                                                const float* __restrict__ emb,
                                                float* __restrict__ out){
  __shared__ __align__(16) float xs[Bt*Dm];
  for (int j = threadIdx.x; j < Bt*Dm; j += 256) xs[j] = xf[j];
  __syncthreads();
  int wave = threadIdx.x>>6, lane = threadIdx.x&63;
  int v = blockIdx.x*4 + wave;
  const float4* e4 = (const float4*)(emb + (size_t)v*Dm);
  float a0=0.f,a1=0.f,a2=0.f,a3=0.f;
  for (int j = lane; j < Dm/4; j += 64){
    float4 ev = e4[j];
    float4 x0 = *(const float4*)&xs[j*4];
    float4 x1 = *(const float4*)&xs[Dm + j*4];
    float4 x2 = *(const float4*)&xs[2*Dm + j*4];
    float4 x3 = *(const float4*)&xs[3*Dm + j*4];
    a0 += ev.x*x0.x + ev.y*x0.y + ev.z*x0.z + ev.w*x0.w;
    a1 += ev.x*x1.x + ev.y*x1.y + ev.z*x1.z + ev.w*x1.w;
    a2 += ev.x*x2.x + ev.y*x2.y + ev.z*x2.z + ev.w*x2.w;
    a3 += ev.x*x3.x + ev.y*x3.y + ev.z*x3.z + ev.w*x3.w;
  }
  #pragma unroll
  for (int off=32; off; off>>=1){
    a0+=__shfl_xor(a0,off); a1+=__shfl_xor(a1,off);
    a2+=__shfl_xor(a2,off); a3+=__shfl_xor(a3,off);
  }
  if (lane==0){
    out[v]        = a0;
    out[Vv+v]     = a1;
    out[2*Vv+v]   = a2;
    out[3*Vv+v]   = a3;
  }
}

extern "C" void kernel_launch(void* const* d_in, const int* in_sizes, int n_in,
                              void* d_out, int out_size, void* d_ws, size_t ws_size,
                              hipStream_t stream){
  const int*   ids   = (const int*)d_in[0];
  const float* emb   = (const float*)d_in[1];
  const float* normw = (const float*)d_in[2];
  const float* inw   = (const float*)d_in[3];
  const float* cw    = (const float*)d_in[4];
  const float* cb    = (const float*)d_in[5];
  const float* xpw   = (const float*)d_in[6];
  const float* dtw   = (const float*)d_in[7];
  const float* dtb   = (const float*)d_in[8];
  const float* alog  = (const float*)d_in[9];
  const float* dpar  = (const float*)d_in[10];
  const float* outw  = (const float*)d_in[11];
  const float* normf = (const float*)d_in[12];
  float* out = (float*)d_out;

  char* p = (char*)d_ws;
  float* h    = (float*)p;  p += (size_t)TOK*Dm*4;        // 25.2 MB
  bf16*  xb   = (bf16*)p;   p += (size_t)TOK*Dm*2;        // 12.6 MB (S aliases tail)
  bf16*  proj = (bf16*)p;   p += (size_t)TOK*2*Im*2;      // 50.3 MB (u|gate; Q/Hin in u cols)
  bf16*  utb  = (bf16*)p;   p += (size_t)TOK*Im*2;        // 25.2 MB
  bf16*  xdbl = (bf16*)p;   p += (size_t)TOK*128*2;       // 2.1 MB
  bf16*  dtq  = (bf16*)p;   p += (size_t)TOK*Im*2;        // 25.2 MB (dt, bf16)
  bf16*  yb   = (bf16*)p;   p += (size_t)TOK*Im*2;        // 25.2 MB
  float* xf   = (float*)p;  p += (size_t)Bt*Dm*4;
  bf16*  inwb = (bf16*)p;   p += (size_t)Lm*2*Im*Dm*2;
  bf16*  outwb= (bf16*)p;   p += (size_t)Lm*Dm*Im*2;
  bf16*  xpwb = (bf16*)p;   p += (size_t)Lm*128*Im*2;
  bf16*  dtwb = (bf16*)p;   p += (size_t)Lm*Im*64*2;      // < proven 222 MB total
  // scan scratch: S (f32, 1.57 MB) aliases xb (dead during scan)
  float* S = (float*)xb;

  { int n = Lm*2*Im*Dm; k_cvt<<<n/1024, 256, 0, stream>>>(inw, inwb, n); }
  { int n = Lm*Dm*Im;   k_cvt<<<n/1024, 256, 0, stream>>>(outw, outwb, n); }
  k_cvt_xpw<<<(Lm*128*Im)/256, 256, 0, stream>>>(xpw, xpwb);
  k_cvt_dtw<<<(Lm*Im*64)/256, 256, 0, stream>>>(dtw, dtwb);

  k_embed<<<TOK, 256, 0, stream>>>(ids, emb, h);

  for (int l = 0; l < Lm; l++){
    k_rmsnorm<<<TOK, 256, 0, stream>>>(h, normw + l*Dm, xb);
    k_gemm256<0><<<dim3((2*Im)/256, TOK/256), 512, 0, stream>>>(
        xb, inwb + (size_t)l*2*Im*Dm, proj, TOK, 2*Im, Dm, Dm, Dm, 2*Im);
    k_conv8<<<TOK, 192, 0, stream>>>(
        proj, cw + (size_t)l*Im*Kc, cb + (size_t)l*Im, utb);
    k_gemm64<<<dim3(1, TOK/64), 256, 0, stream>>>(
        utb, xpwb + (size_t)l*128*Im, xdbl, TOK, 128, Im, Im, Im, 128);
    k_gemm<3><<<dim3(Im/128, TOK/128), 256, 0, stream>>>(
        xdbl, dtwb + (size_t)l*Im*64, dtq, dtb + (size_t)l*Im, TOK, Im, 64, 128, 64, Im);
    // chunked scan (Q rows [0,QROWS), Hin rows [QROWS,2*QROWS) in proj u-columns)
    k_scan1<<<dim3(Im/256, Bt, NC), 256, 0, stream>>>(
        dtq, utb, xdbl, alog + (size_t)l*Im*Nst, proj, S);
    k_scan2<<<(Bt*Nst*Im)/256, 256, 0, stream>>>(
        proj, S, alog + (size_t)l*Im*Nst, proj);
    k_scan3<<<dim3(Im/256, Bt, NC), 256, 0, stream>>>(
        dtq, utb, xdbl, proj, alog + (size_t)l*Im*Nst, dpar + (size_t)l*Im, proj, yb);
    k_gemm256n<<<dim3(Dm/256, TOK/128), 512, 0, stream>>>(
        yb, outwb + (size_t)l*Dm*Im, h, TOK, Dm, Im, Im, Im, Dm);
  }

  k_rms_last<<<Bt, 256, 0, stream>>>(h, normf, xf);
  k_logits<<<Vv/4, 256, 0, stream>>>(xf, emb, out);
}